// Round 1
// baseline (139.072 us; speedup 1.0000x reference)
//
#include <hip/hip_runtime.h>

#define NUM_CLASS 4096
#define HIDDEN    512
#define NGROUPS   64
#define BATCH     64

// ws layout (ints):
//   [0..1]              nwork[2]
//   [16 .. 16+1024)     work[2][512]   packed: (g<<20)|(ncls<<12)|c0
//   [2048 .. 2048+8192) inv[2][4096]
#define WS_NWORK 0
#define WS_WORK  16
#define WS_INV   2048

__global__ __launch_bounds__(256) void prep_kernel(
    const int* __restrict__ co_gof, const int* __restrict__ cl_gof,
    const int* __restrict__ co_idx, const int* __restrict__ cl_idx,
    int* __restrict__ ws)
{
    __shared__ int s_starts[2][65];
    int tid = threadIdx.x;
    for (int v = tid; v < 2 * NUM_CLASS; v += 256) {
        int h = v >> 12;
        int c = v & (NUM_CLASS - 1);
        const int* gof = (h == 0) ? co_gof : cl_gof;
        int g = gof[c];
        if (c == 0) { s_starts[h][0] = 0; s_starts[h][64] = NUM_CLASS; }
        else if (g != gof[c - 1]) s_starts[h][g] = c;
        const int* idx = (h == 0) ? co_idx : cl_idx;
        ws[WS_INV + h * NUM_CLASS + idx[c]] = c;   // inv[index[j]] = j
    }
    __syncthreads();
    if (tid < 2) {
        int h = tid;
        int n = 0;
        for (int g = 0; g < NGROUPS; ++g) {
            int s = s_starts[h][g], e = s_starts[h][g + 1];
            for (int c0 = s; c0 < e; c0 += 64) {
                int ncls = min(64, e - c0);
                ws[WS_WORK + h * 512 + n] = (g << 20) | (ncls << 12) | c0;
                ++n;
            }
        }
        ws[WS_NWORK + h] = n;
    }
}

#define LOADC(T, RX, RW) do {                                                   \
    int k0_ = (T) * 64;                                                         \
    _Pragma("unroll")                                                           \
    for (int q = 0; q < 4; ++q) {                                               \
        int v = q * 256 + tid; int bq = v >> 4; int kv = v & 15;                \
        RX[q] = *(const float4*)(x + (size_t)(bq * 128 + row) * 512 + k0_ + kv * 4); \
        int ci = min(bq, ncls - 1);                                             \
        RW[q] = *(const float4*)(Wp + (size_t)(c0 + ci) * 512 + k0_ + kv * 4);  \
    } } while (0)

#define STOREC(RX, RW) do {                                                     \
    _Pragma("unroll")                                                           \
    for (int q = 0; q < 4; ++q) {                                               \
        int v = q * 256 + tid; int bq = v >> 4; int kv = v & 15;                \
        *(float4*)&Xs[bq][kv * 4] = RX[q];                                      \
        *(float4*)&Ws[bq][kv * 4] = RW[q];                                      \
    } } while (0)

#define COMPUTEC() do {                                                         \
    _Pragma("unroll")                                                           \
    for (int kq = 0; kq < 16; ++kq) {                                           \
        float4 a_[4], w_[4];                                                    \
        _Pragma("unroll")                                                       \
        for (int i = 0; i < 4; ++i) a_[i] = *(const float4*)&Xs[ty + 16 * i][kq * 4]; \
        _Pragma("unroll")                                                       \
        for (int j = 0; j < 4; ++j) w_[j] = *(const float4*)&Ws[tx + 16 * j][kq * 4]; \
        _Pragma("unroll")                                                       \
        for (int i = 0; i < 4; ++i)                                             \
        _Pragma("unroll")                                                       \
        for (int j = 0; j < 4; ++j) {                                           \
            acc[i][j].x += a_[i].x * w_[j].x;                                   \
            acc[i][j].y += a_[i].y * w_[j].y;                                   \
            acc[i][j].z += a_[i].z * w_[j].z;                                   \
            acc[i][j].w += a_[i].w * w_[j].w;                                   \
        }                                                                       \
    } } while (0)

__global__ __launch_bounds__(256) void gwl_main_kernel(
    const float* __restrict__ x,
    const float* __restrict__ co_W, const float* __restrict__ cl_W,
    const float* __restrict__ co_b, const float* __restrict__ cl_b,
    const int* __restrict__ ws,
    float* __restrict__ out)
{
    int h    = blockIdx.x & 1;
    int widx = blockIdx.x >> 1;
    int nw = ws[WS_NWORK + h];
    if (widx >= nw) return;
    int packed = ws[WS_WORK + h * 512 + widx];
    int c0   = packed & 0xFFF;
    int ncls = (packed >> 12) & 0xFF;
    int g    = packed >> 20;

    const float* Wp   = h ? cl_W : co_W;
    const float* bias = h ? cl_b : co_b;
    const int*   inv  = ws + WS_INV + h * NUM_CLASS;
    int row = h * 64 + g;   // row index inside x's middle dim (128)

    __shared__ float Xs[64][68];
    __shared__ float Ws[64][68];

    int tid = threadIdx.x;
    int tx = tid & 15;   // class dim base
    int ty = tid >> 4;   // batch dim base

    float4 rxA[4], rwA[4], rxB[4], rwB[4];
    float4 acc[4][4];
    #pragma unroll
    for (int i = 0; i < 4; ++i)
        #pragma unroll
        for (int j = 0; j < 4; ++j) acc[i][j] = make_float4(0.f, 0.f, 0.f, 0.f);

    LOADC(0, rxA, rwA);

    #pragma unroll 1
    for (int t = 0; t < 8; t += 2) {
        __syncthreads();
        STOREC(rxA, rwA);
        __syncthreads();
        LOADC(t + 1, rxB, rwB);
        COMPUTEC();
        __syncthreads();
        STOREC(rxB, rwB);
        __syncthreads();
        if (t + 2 < 8) LOADC(t + 2, rxA, rwA);
        COMPUTEC();
    }

    float* outh = out + (size_t)h * BATCH * NUM_CLASS;
    #pragma unroll
    for (int j = 0; j < 4; ++j) {
        int cl = tx + 16 * j;
        if (cl < ncls) {
            int c  = c0 + cl;
            int oc = inv[c];
            float bb = bias[c];
            #pragma unroll
            for (int i = 0; i < 4; ++i) {
                int b = ty + 16 * i;
                float4 s4 = acc[i][j];
                outh[(size_t)b * NUM_CLASS + oc] = s4.x + s4.y + s4.z + s4.w + bb;
            }
        }
    }
}

extern "C" void kernel_launch(void* const* d_in, const int* in_sizes, int n_in,
                              void* d_out, int out_size, void* d_ws, size_t ws_size,
                              hipStream_t stream)
{
    (void)in_sizes; (void)n_in; (void)out_size; (void)ws_size;
    const float* x     = (const float*)d_in[0];
    const float* co_W  = (const float*)d_in[1];
    const float* cl_W  = (const float*)d_in[2];
    const float* co_b  = (const float*)d_in[3];
    const float* cl_b  = (const float*)d_in[4];
    const int*   co_gof = (const int*)d_in[5];
    const int*   cl_gof = (const int*)d_in[6];
    const int*   co_idx = (const int*)d_in[7];
    const int*   cl_idx = (const int*)d_in[8];
    int*   ws  = (int*)d_ws;
    float* out = (float*)d_out;

    hipLaunchKernelGGL(prep_kernel, dim3(1), dim3(256), 0, stream,
                       co_gof, cl_gof, co_idx, cl_idx, ws);
    hipLaunchKernelGGL(gwl_main_kernel, dim3(256), dim3(256), 0, stream,
                       x, co_W, cl_W, co_b, cl_b, ws, out);
}

// Round 2
// 85.029 us; speedup vs baseline: 1.6356x; 1.6356x over previous
//
#include <hip/hip_runtime.h>

#define NUM_CLASS 4096
#define HIDDEN    512
#define NGROUPS   64
#define BATCH     64

// ws layout:
//   ints:  [0..1]  nwork[2]
//          [16 .. 16+1024)   work[2][512]  packed (g<<20)|(ncls<<12)|c0
//          [2048 .. 2048+8192) inv[2][4096]  (scatter fallback only)
//   floats from byte 65536: tmp[KSPLIT][2][64][4096]
#define WS_NWORK 0
#define WS_WORK  16
#define WS_INV   2048
#define TMP_OFF_F 16384          // float index of tmp (byte 65536)
#define TMP_HALF_STRIDE 524288   // floats per ksplit slice: 2*64*4096

__global__ __launch_bounds__(256) void prep_kernel(
    const int* __restrict__ co_gof, const int* __restrict__ cl_gof,
    const int* __restrict__ co_idx, const int* __restrict__ cl_idx,
    int* __restrict__ ws)
{
    __shared__ int s_starts[2][65];
    int tid = threadIdx.x;
    for (int v = tid; v < 2 * NUM_CLASS; v += 256) {
        int h = v >> 12;
        int c = v & (NUM_CLASS - 1);
        const int* gof = (h == 0) ? co_gof : cl_gof;
        int g = gof[c];
        if (c == 0) { s_starts[h][0] = 0; s_starts[h][64] = NUM_CLASS; }
        else if (g != gof[c - 1]) s_starts[h][g] = c;
        const int* idx = (h == 0) ? co_idx : cl_idx;
        ws[WS_INV + h * NUM_CLASS + idx[c]] = c;   // inv[index[j]] = j
    }
    __syncthreads();
    if (tid < 64) {
        int lane = tid;
        for (int h = 0; h < 2; ++h) {
            int s = s_starts[h][lane];
            int e = s_starts[h][lane + 1];
            int cnt = (e - s + 63) >> 6;
            // inclusive scan over 64 lanes
            int inc = cnt;
            #pragma unroll
            for (int d = 1; d < 64; d <<= 1) {
                int o = __shfl_up(inc, d, 64);
                if (lane >= d) inc += o;
            }
            int excl = inc - cnt;
            for (int t = 0; t < cnt; ++t) {
                int c0 = s + t * 64;
                int ncls = min(64, e - c0);
                ws[WS_WORK + h * 512 + excl + t] = (lane << 20) | (ncls << 12) | c0;
            }
            if (lane == 63) ws[WS_NWORK + h] = inc;
        }
    }
}

#define LOADC(K0) do {                                                          \
    int k0_ = (K0);                                                             \
    _Pragma("unroll")                                                           \
    for (int q = 0; q < 4; ++q) {                                               \
        int v = q * 256 + tid; int bq = v >> 4; int kv = v & 15;                \
        rx[q] = *(const float4*)(x + (bq * 128 + row) * 512 + k0_ + kv * 4);    \
        int ci = min(bq, ncls - 1);                                             \
        rw[q] = *(const float4*)(Wp + (c0 + ci) * 512 + k0_ + kv * 4);          \
    } } while (0)

#define STOREC() do {                                                           \
    _Pragma("unroll")                                                           \
    for (int q = 0; q < 4; ++q) {                                               \
        int v = q * 256 + tid; int bq = v >> 4; int kv = v & 15;                \
        *(float4*)&Xs[bq][kv * 4] = rx[q];                                      \
        *(float4*)&Ws[bq][kv * 4] = rw[q];                                      \
    } } while (0)

#define COMPUTEC() do {                                                         \
    _Pragma("unroll")                                                           \
    for (int kq = 0; kq < 16; ++kq) {                                           \
        float4 a_[4], w_[4];                                                    \
        _Pragma("unroll")                                                       \
        for (int i = 0; i < 4; ++i) a_[i] = *(const float4*)&Xs[ty + 16 * i][kq * 4]; \
        _Pragma("unroll")                                                       \
        for (int j = 0; j < 4; ++j) w_[j] = *(const float4*)&Ws[tx + 16 * j][kq * 4]; \
        _Pragma("unroll")                                                       \
        for (int i = 0; i < 4; ++i)                                             \
        _Pragma("unroll")                                                       \
        for (int j = 0; j < 4; ++j) {                                           \
            acc[i][j].x += a_[i].x * w_[j].x;                                   \
            acc[i][j].y += a_[i].y * w_[j].y;                                   \
            acc[i][j].z += a_[i].z * w_[j].z;                                   \
            acc[i][j].w += a_[i].w * w_[j].w;                                   \
        }                                                                       \
    } } while (0)

// KSPLIT in {1,2,4}; SCATTER fallback writes permuted output directly (+bias)
template<int KSPLIT, bool SCATTER>
__global__ __launch_bounds__(256, 3) void gwl_stage1(
    const float* __restrict__ x,
    const float* __restrict__ co_W, const float* __restrict__ cl_W,
    const float* __restrict__ co_b, const float* __restrict__ cl_b,
    int* __restrict__ ws, float* __restrict__ out)
{
    int widx = blockIdx.x;
    int h    = blockIdx.y;
    int kh   = blockIdx.z;
    int nw = ws[WS_NWORK + h];
    if (widx >= nw) return;
    int packed = ws[WS_WORK + h * 512 + widx];
    int c0   = packed & 0xFFF;
    int ncls = (packed >> 12) & 0xFF;
    int g    = packed >> 20;

    const float* Wp = h ? cl_W : co_W;
    int row = h * 64 + g;

    __shared__ float Xs[64][68];
    __shared__ float Ws[64][68];

    int tid = threadIdx.x;
    int tx = tid & 15;
    int ty = tid >> 4;

    float4 rx[4], rw[4];
    float4 acc[4][4];
    #pragma unroll
    for (int i = 0; i < 4; ++i)
        #pragma unroll
        for (int j = 0; j < 4; ++j) acc[i][j] = make_float4(0.f, 0.f, 0.f, 0.f);

    const int NCH = 8 / KSPLIT;
    const int kbase = kh * NCH * 64;

    LOADC(kbase);
    #pragma unroll 1
    for (int t = 0; t < NCH; ++t) {
        __syncthreads();
        STOREC();
        __syncthreads();
        if (t + 1 < NCH) LOADC(kbase + (t + 1) * 64);
        COMPUTEC();
    }

    if (!SCATTER) {
        float* tmp = (float*)ws + TMP_OFF_F
                   + (size_t)(kh * 2 + h) * (64 * 4096);
        #pragma unroll
        for (int j = 0; j < 4; ++j) {
            int cl = tx + 16 * j;
            if (cl < ncls) {
                int c = c0 + cl;
                #pragma unroll
                for (int i = 0; i < 4; ++i) {
                    int b = ty + 16 * i;
                    float4 s4 = acc[i][j];
                    tmp[b * 4096 + c] = s4.x + s4.y + s4.z + s4.w;
                }
            }
        }
    } else {
        const float* bias = h ? cl_b : co_b;
        const int*   inv  = ws + WS_INV + h * NUM_CLASS;
        float* outh = out + (size_t)h * BATCH * NUM_CLASS;
        #pragma unroll
        for (int j = 0; j < 4; ++j) {
            int cl = tx + 16 * j;
            if (cl < ncls) {
                int c  = c0 + cl;
                int oc = inv[c];
                float bb = bias[c];
                #pragma unroll
                for (int i = 0; i < 4; ++i) {
                    int b = ty + 16 * i;
                    float4 s4 = acc[i][j];
                    outh[b * 4096 + oc] = s4.x + s4.y + s4.z + s4.w + bb;
                }
            }
        }
    }
}

template<int KSPLIT>
__global__ __launch_bounds__(256) void gwl_permute(
    const int* __restrict__ ws,
    const float* __restrict__ co_b, const float* __restrict__ cl_b,
    const int* __restrict__ co_idx, const int* __restrict__ cl_idx,
    float* __restrict__ out)
{
    int jh = blockIdx.x;          // 0..1
    int b  = blockIdx.y;          // 0..63
    int h  = blockIdx.z;          // 0..1
    const float* bias = h ? cl_b : co_b;
    const int*   idx  = h ? cl_idx : co_idx;
    const float* tmp  = (const float*)ws + TMP_OFF_F + (size_t)h * (64 * 4096)
                      + (size_t)b * 4096;
    float* orow = out + ((size_t)h * 64 + b) * 4096;
    int tid = threadIdx.x;
    int j0 = jh * 2048;
    #pragma unroll
    for (int u = 0; u < 8; ++u) {
        int j = j0 + u * 256 + tid;
        int c = idx[j];
        float v = bias[c];
        #pragma unroll
        for (int s = 0; s < KSPLIT; ++s)
            v += tmp[(size_t)s * TMP_HALF_STRIDE + c];
        orow[j] = v;
    }
}

extern "C" void kernel_launch(void* const* d_in, const int* in_sizes, int n_in,
                              void* d_out, int out_size, void* d_ws, size_t ws_size,
                              hipStream_t stream)
{
    (void)in_sizes; (void)n_in; (void)out_size;
    const float* x      = (const float*)d_in[0];
    const float* co_W   = (const float*)d_in[1];
    const float* cl_W   = (const float*)d_in[2];
    const float* co_b   = (const float*)d_in[3];
    const float* cl_b   = (const float*)d_in[4];
    const int*   co_gof = (const int*)d_in[5];
    const int*   cl_gof = (const int*)d_in[6];
    const int*   co_idx = (const int*)d_in[7];
    const int*   cl_idx = (const int*)d_in[8];
    int*   ws  = (int*)d_ws;
    float* out = (float*)d_out;

    hipLaunchKernelGGL(prep_kernel, dim3(1), dim3(256), 0, stream,
                       co_gof, cl_gof, co_idx, cl_idx, ws);

    const size_t base = 65536;
    const size_t buf  = (size_t)2 * 64 * 4096 * 4;   // 2 MiB per ksplit slice
    int KS = (ws_size >= base + 4 * buf) ? 4
           : (ws_size >= base + 2 * buf) ? 2
           : (ws_size >= base + 1 * buf) ? 1 : 0;

    if (KS == 4) {
        hipLaunchKernelGGL((gwl_stage1<4, false>), dim3(128, 2, 4), dim3(256), 0, stream,
                           x, co_W, cl_W, co_b, cl_b, ws, out);
        hipLaunchKernelGGL((gwl_permute<4>), dim3(2, 64, 2), dim3(256), 0, stream,
                           ws, co_b, cl_b, co_idx, cl_idx, out);
    } else if (KS == 2) {
        hipLaunchKernelGGL((gwl_stage1<2, false>), dim3(128, 2, 2), dim3(256), 0, stream,
                           x, co_W, cl_W, co_b, cl_b, ws, out);
        hipLaunchKernelGGL((gwl_permute<2>), dim3(2, 64, 2), dim3(256), 0, stream,
                           ws, co_b, cl_b, co_idx, cl_idx, out);
    } else if (KS == 1) {
        hipLaunchKernelGGL((gwl_stage1<1, false>), dim3(128, 2, 1), dim3(256), 0, stream,
                           x, co_W, cl_W, co_b, cl_b, ws, out);
        hipLaunchKernelGGL((gwl_permute<1>), dim3(2, 64, 2), dim3(256), 0, stream,
                           ws, co_b, cl_b, co_idx, cl_idx, out);
    } else {
        hipLaunchKernelGGL((gwl_stage1<1, true>), dim3(128, 2, 1), dim3(256), 0, stream,
                           x, co_W, cl_W, co_b, cl_b, ws, out);
    }
}

// Round 3
// 31.165 us; speedup vs baseline: 4.4624x; 2.7283x over previous
//
#include <hip/hip_runtime.h>
#include <hip/hip_bf16.h>
#include <string.h>

#define NUM_CLASS 4096
#define HIDDEN    512
#define NGROUPS   64
#define BATCH     64

// ws layout (int offsets):
//   [0..1]            nwork[2]
//   [16..271]         work[2][128] packed (g<<20)|(ncls<<12)|c0
//   [2048..10239]     srcoff[2][4096]  = widx*4096 + slot
//   [10240..18431]    inv[2][4096]     (scatter fallback only)
//   float idx 32768+: tmp[s][h][widx<128][4096]  dense 64b x 64slot tiles
#define WS_NWORK 0
#define WS_WORK  16
#define WS_SRC   2048
#define WS_INV   10240
#define TMP_OFF_F 32768
#define TMP_H_STRIDE (128*4096)      // floats
#define TMP_S_STRIDE (2*128*4096)    // floats

typedef __attribute__((ext_vector_type(8))) short short8;
typedef __attribute__((ext_vector_type(4))) float f32x4;

__device__ __forceinline__ unsigned int pack2bf(float a, float b) {
    __hip_bfloat16 ha = __float2bfloat16(a), hb = __float2bfloat16(b);
    unsigned short ua, ub;
    memcpy(&ua, &ha, 2); memcpy(&ub, &hb, 2);
    return (unsigned int)ua | ((unsigned int)ub << 16);
}

__global__ __launch_bounds__(1024) void prep_kernel(
    const int* __restrict__ co_gof, const int* __restrict__ cl_gof,
    const int* __restrict__ co_idx, const int* __restrict__ cl_idx,
    int* __restrict__ ws)
{
    __shared__ int s_starts[2][65];
    __shared__ int s_wbase[2][64];
    int tid = threadIdx.x;
    for (int v = tid; v < 2 * NUM_CLASS; v += 1024) {
        int h = v >> 12, c = v & (NUM_CLASS - 1);
        const int* gof = h ? cl_gof : co_gof;
        int g = gof[c];
        if (c == 0) { s_starts[h][0] = 0; s_starts[h][64] = NUM_CLASS; }
        else if (g != gof[c - 1]) s_starts[h][g] = c;
    }
    __syncthreads();
    if (tid < 64) {
        int lane = tid;
        for (int h = 0; h < 2; ++h) {
            int s = s_starts[h][lane], e = s_starts[h][lane + 1];
            int cnt = (e - s + 63) >> 6;
            int inc = cnt;
            #pragma unroll
            for (int d = 1; d < 64; d <<= 1) {
                int o = __shfl_up(inc, d, 64);
                if (lane >= d) inc += o;
            }
            int excl = inc - cnt;
            s_wbase[h][lane] = excl;
            for (int t = 0; t < cnt; ++t) {
                int c0 = s + t * 64;
                int ncls = min(64, e - c0);
                ws[WS_WORK + h * 128 + excl + t] = (lane << 20) | (ncls << 12) | c0;
            }
            if (lane == 63) ws[WS_NWORK + h] = inc;
        }
    }
    __syncthreads();
    for (int v = tid; v < 2 * NUM_CLASS; v += 1024) {
        int h = v >> 12, c = v & (NUM_CLASS - 1);
        const int* gof = h ? cl_gof : co_gof;
        const int* idx = h ? cl_idx : co_idx;
        int g = gof[c];
        int rel = c - s_starts[h][g];
        ws[WS_SRC + v] = (s_wbase[h][g] + (rel >> 6)) * 4096 + (rel & 63);
        ws[WS_INV + h * NUM_CLASS + idx[c]] = c;
    }
}

// KS in {1,2}: K split across blockIdx.z. SCATTER: direct permuted out (+bias).
template<int KS, bool SCATTER>
__global__ __launch_bounds__(256, 4) void gwl_stage1(
    const float* __restrict__ x,
    const float* __restrict__ co_W, const float* __restrict__ cl_W,
    const float* __restrict__ co_b, const float* __restrict__ cl_b,
    int* __restrict__ ws, float* __restrict__ out)
{
    int widx = blockIdx.x, h = blockIdx.y, kh = blockIdx.z;
    int nw = ws[WS_NWORK + h];
    if (widx >= nw) return;
    int packed = ws[WS_WORK + h * 128 + widx];
    int c0 = packed & 0xFFF, ncls = (packed >> 12) & 0xFF, g = packed >> 20;
    const float* Wp = h ? cl_W : co_W;
    int xrow = h * 64 + g;

    __shared__ __align__(16) unsigned char smem[18432];
    unsigned short (*Xs)[72]  = (unsigned short(*)[72])smem;
    unsigned short (*Wls)[72] = (unsigned short(*)[72])(smem + 9216);

    int tid = threadIdx.x;
    int l = tid & 63, w = tid >> 6;

    int rowq[4], kvq[4], wcl[4];
    #pragma unroll
    for (int q = 0; q < 4; ++q) {
        int v = q * 256 + tid;
        rowq[q] = v >> 4;
        kvq[q]  = v & 15;
        wcl[q]  = min(rowq[q], ncls - 1);
    }

    float4 rx[4], rw[4];
    f32x4 acc[4];
    #pragma unroll
    for (int i = 0; i < 4; ++i) acc[i] = (f32x4)(0.0f);

    const int NCH = 8 / KS;
    const int kbase = kh * (HIDDEN / KS);

#define LOADC(K0) do {                                                              \
    int k0_ = (K0);                                                                 \
    _Pragma("unroll")                                                               \
    for (int q = 0; q < 4; ++q) {                                                   \
        rx[q] = *(const float4*)(x + rowq[q] * 65536 + xrow * 512 + k0_ + kvq[q]*4);\
        rw[q] = *(const float4*)(Wp + (c0 + wcl[q]) * 512 + k0_ + kvq[q] * 4);      \
    } } while (0)

#define STOREC() do {                                                               \
    _Pragma("unroll")                                                               \
    for (int q = 0; q < 4; ++q) {                                                   \
        unsigned int x0 = pack2bf(rx[q].x, rx[q].y);                                \
        unsigned int x1 = pack2bf(rx[q].z, rx[q].w);                                \
        unsigned int w0 = pack2bf(rw[q].x, rw[q].y);                                \
        unsigned int w1 = pack2bf(rw[q].z, rw[q].w);                                \
        *(uint2*)&Xs[rowq[q]][kvq[q] * 4]  = make_uint2(x0, x1);                    \
        *(uint2*)&Wls[rowq[q]][kvq[q] * 4] = make_uint2(w0, w1);                    \
    } } while (0)

#define COMPUTEC() do {                                                             \
    _Pragma("unroll")                                                               \
    for (int kq = 0; kq < 2; ++kq) {                                                \
        int koff = kq * 32 + (l >> 4) * 8;                                          \
        short8 bfrag = *(const short8*)&Wls[w * 16 + (l & 15)][koff];               \
        _Pragma("unroll")                                                           \
        for (int i = 0; i < 4; ++i) {                                               \
            short8 afrag = *(const short8*)&Xs[16 * i + (l & 15)][koff];            \
            acc[i] = __builtin_amdgcn_mfma_f32_16x16x32_bf16(afrag, bfrag, acc[i],  \
                                                             0, 0, 0);              \
        }                                                                           \
    } } while (0)

    LOADC(kbase);
    #pragma unroll 1
    for (int t = 0; t < NCH; ++t) {
        STOREC();
        __syncthreads();
        if (t + 1 < NCH) LOADC(kbase + (t + 1) * 64);
        COMPUTEC();
        __syncthreads();
    }

    // epilogue: acc -> LDS f32 tile -> dense coalesced writes
    float (*ftile)[68] = (float(*)[68])smem;   // 64*68*4 = 17408 <= 18432
    #pragma unroll
    for (int i = 0; i < 4; ++i)
        #pragma unroll
        for (int r = 0; r < 4; ++r)
            ftile[16 * i + (l >> 4) * 4 + r][w * 16 + (l & 15)] = acc[i][r];
    __syncthreads();

    if (!SCATTER) {
        float* tile = (float*)ws + TMP_OFF_F
                    + (size_t)(kh * 2 + h) * TMP_H_STRIDE + (size_t)widx * 4096;
        #pragma unroll
        for (int p = 0; p < 4; ++p) {
            int row = p * 16 + (tid >> 4);
            int c4  = (tid & 15) * 4;
            *(float4*)&tile[row * 64 + c4] = *(const float4*)&ftile[row][c4];
        }
    } else {
        const float* bias = h ? cl_b : co_b;
        const int*   inv  = ws + WS_INV + h * NUM_CLASS;
        float* outh = out + (size_t)h * BATCH * NUM_CLASS;
        #pragma unroll
        for (int p = 0; p < 4; ++p) {
            int row = p * 16 + (tid >> 4);
            int c4  = (tid & 15) * 4;
            float4 v = *(const float4*)&ftile[row][c4];
            const float* ve = (const float*)&v;
            #pragma unroll
            for (int e = 0; e < 4; ++e) {
                int slot = c4 + e;
                if (slot < ncls) {
                    int c = c0 + slot;
                    outh[row * 4096 + inv[c]] = ve[e] + bias[c];
                }
            }
        }
    }
#undef LOADC
#undef STOREC
#undef COMPUTEC
}

template<int KS>
__global__ __launch_bounds__(256) void gwl_permute(
    const int* __restrict__ ws,
    const float* __restrict__ co_b, const float* __restrict__ cl_b,
    const int* __restrict__ co_idx, const int* __restrict__ cl_idx,
    float* __restrict__ out)
{
    int jh = blockIdx.x;   // 0..1
    int b  = blockIdx.y;   // 0..63
    int h  = blockIdx.z;   // 0..1
    const float* bias = h ? cl_b : co_b;
    const int*   idx  = h ? cl_idx : co_idx;
    const int* srcoff = ws + WS_SRC + h * NUM_CLASS;
    const float* tmpb = (const float*)ws + TMP_OFF_F
                      + (size_t)h * TMP_H_STRIDE + (size_t)b * 64;
    float* orow = out + ((size_t)h * 64 + b) * 4096;
    int tid = threadIdx.x;
    #pragma unroll
    for (int u = 0; u < 8; ++u) {
        int j = jh * 2048 + u * 256 + tid;
        int c = idx[j];
        int so = srcoff[c];
        float v = bias[c];
        #pragma unroll
        for (int s = 0; s < KS; ++s)
            v += tmpb[(size_t)s * TMP_S_STRIDE + so];
        orow[j] = v;
    }
}

extern "C" void kernel_launch(void* const* d_in, const int* in_sizes, int n_in,
                              void* d_out, int out_size, void* d_ws, size_t ws_size,
                              hipStream_t stream)
{
    (void)in_sizes; (void)n_in; (void)out_size;
    const float* x      = (const float*)d_in[0];
    const float* co_W   = (const float*)d_in[1];
    const float* cl_W   = (const float*)d_in[2];
    const float* co_b   = (const float*)d_in[3];
    const float* cl_b   = (const float*)d_in[4];
    const int*   co_gof = (const int*)d_in[5];
    const int*   cl_gof = (const int*)d_in[6];
    const int*   co_idx = (const int*)d_in[7];
    const int*   cl_idx = (const int*)d_in[8];
    int*   ws  = (int*)d_ws;
    float* out = (float*)d_out;

    hipLaunchKernelGGL(prep_kernel, dim3(1), dim3(1024), 0, stream,
                       co_gof, cl_gof, co_idx, cl_idx, ws);

    const size_t base  = (size_t)TMP_OFF_F * 4;
    const size_t slice = (size_t)TMP_S_STRIDE * 4;   // 4 MiB
    if (ws_size >= base + 2 * slice) {
        hipLaunchKernelGGL((gwl_stage1<2, false>), dim3(128, 2, 2), dim3(256), 0, stream,
                           x, co_W, cl_W, co_b, cl_b, ws, out);
        hipLaunchKernelGGL((gwl_permute<2>), dim3(2, 64, 2), dim3(256), 0, stream,
                           ws, co_b, cl_b, co_idx, cl_idx, out);
    } else if (ws_size >= base + 1 * slice) {
        hipLaunchKernelGGL((gwl_stage1<1, false>), dim3(128, 2, 1), dim3(256), 0, stream,
                           x, co_W, cl_W, co_b, cl_b, ws, out);
        hipLaunchKernelGGL((gwl_permute<1>), dim3(2, 64, 2), dim3(256), 0, stream,
                           ws, co_b, cl_b, co_idx, cl_idx, out);
    } else {
        hipLaunchKernelGGL((gwl_stage1<1, true>), dim3(128, 2, 1), dim3(256), 0, stream,
                           x, co_W, cl_W, co_b, cl_b, ws, out);
    }
}